// Round 2
// baseline (154.598 us; speedup 1.0000x reference)
//
#include <hip/hip_runtime.h>

// Single-level deformable attention.
// value: (bs=16, K=2500, H=8, D=32) f32
// sampling_locations: (bs, Q=2000, H=8, L=1, P=4, 2) f32
// attention_weights:  (bs, Q, H, 1, P) f32
// out: (bs, Q, H*D=256) f32
//
// R1: 32-lane/(b,q,h) scalar -> 49.7us, VALU-bound (75%).
// R2: 8-lane/(b,q,h) float4  -> 46us, VALU 24%, HBM 46%: latency-bound.
// R3: XCD swizzle (batch pinned to XCD): FETCH 138->27MB but dur 42us.
// R4: launch_bounds(256,2), 2 q/thread, SGPR-base: 42us, VGPR=32, MLP~4.
// R5: inline-asm 32 loads in flight + counted vmcnt: 42.5us, VGPR=100,
//     occupancy 17%. Three kernels all ~42us => per-CU VMEM gather
//     address-processing limit (~1.25 lane-req/cy/CU). L2-gather path is
//     throughput-capped, not latency-capped.
// R6: LDS-staged gather. Block = (b, h, cg) with cg = 4-channel group:
//     value[b, :, h, cg*4..+3] = 2500 x 16B = 40,000 B static LDS.
//     Grid 1024 = 16b x 8h x 8cg, 4 blocks/CU, 256 thr; thread owns one
//     query per pass (8 passes): 16x ds_read_b128 + 64 FMA, no reduce.
//     blockIdx = cg*128 + b*8 + h  => blockIdx%8 = h => all 8 cg-blocks
//     of (b,h) on the SAME XCD: their 16B stores/stage-reads merge to
//     full 128B lines in that XCD's L2.

#define FH 50
#define FW 50
#define KK (FH * FW)   // 2500
#define NH 8
#define ND 32
#define NQ 2000
#define NP 4
#define TPB 256
#define NPASS ((NQ + TPB - 1) / TPB)   // 8

typedef float f32x4 __attribute__((ext_vector_type(4)));

__global__ __launch_bounds__(TPB, 4) void deform_attn_kernel(
    const float* __restrict__ value,
    const float* __restrict__ loc,
    const float* __restrict__ attw,
    float* __restrict__ out)
{
    // blockIdx = cg*128 + b*8 + h
    const int id = blockIdx.x;
    const int cg = id >> 7;          // 0..7  (4-channel group)
    const int bh = id & 127;
    const int b  = bh >> 3;
    const int h  = bh & 7;

    __shared__ f32x4 lds[KK];        // 40,000 B

    const int t = threadIdx.x;

    // ---- stage value[b, k, h, cg*4 .. cg*4+3] -> lds[k] ----
    {
        // f32x4 units: row stride per k = 256 floats / 4 = 64
        const f32x4* __restrict__ src =
            (const f32x4*)value + (size_t)b * KK * 64 + h * 8 + cg;
#pragma unroll
        for (int i = 0; i < 10; ++i) {           // 10*256 >= 2500
            const int k = i * TPB + t;
            if (k < KK) lds[k] = src[(size_t)k * 64];
        }
    }
    __syncthreads();

    const f32x4* __restrict__ lp = (const f32x4*)loc;
    const f32x4* __restrict__ ap = (const f32x4*)attw;
    f32x4* __restrict__ op = (f32x4*)out;

    for (int pass = 0; pass < NPASS; ++pass) {
        const int q = pass * TPB + t;
        if (q >= NQ) break;          // only last pass diverges (tail 208/256)

        const int gid = (b * NQ + q) * NH + h;
        const f32x4 l0 = lp[(size_t)gid * 2 + 0];
        const f32x4 l1 = lp[(size_t)gid * 2 + 1];
        const f32x4 a4 = ap[gid];

        const float pxx[NP] = {l0.x, l0.z, l1.x, l1.z};
        const float pyy[NP] = {l0.y, l0.w, l1.y, l1.w};
        const float awp[NP] = {a4.x, a4.y, a4.z, a4.w};

        int   idx[16];
        float wts[16];
#pragma unroll
        for (int p = 0; p < NP; ++p) {
            const float fx = pxx[p] * (float)FW - 0.5f;
            const float fy = pyy[p] * (float)FH - 0.5f;
            const float x0f = floorf(fx);
            const float y0f = floorf(fy);
            const int x0 = (int)x0f, y0 = (int)y0f;
            const int x1 = x0 + 1, y1 = y0 + 1;
            const float wx1 = fx - x0f, wx0 = 1.f - wx1;
            const float wy1 = fy - y0f, wy0 = 1.f - wy1;

            const bool vx0 = (x0 >= 0) & (x0 < FW);
            const bool vx1 = (x1 >= 0) & (x1 < FW);
            const bool vy0 = (y0 >= 0) & (y0 < FH);
            const bool vy1 = (y1 >= 0) & (y1 < FH);

            const int cx0 = min(max(x0, 0), FW - 1);
            const int cx1 = min(max(x1, 0), FW - 1);
            const int cy0 = min(max(y0, 0), FH - 1);
            const int cy1 = min(max(y1, 0), FH - 1);

            idx[p * 4 + 0] = cy0 * FW + cx0;
            idx[p * 4 + 1] = cy0 * FW + cx1;
            idx[p * 4 + 2] = cy1 * FW + cx0;
            idx[p * 4 + 3] = cy1 * FW + cx1;

            wts[p * 4 + 0] = ((vx0 & vy0) ? (wx0 * wy0) : 0.f) * awp[p];
            wts[p * 4 + 1] = ((vx1 & vy0) ? (wx1 * wy0) : 0.f) * awp[p];
            wts[p * 4 + 2] = ((vx0 & vy1) ? (wx0 * wy1) : 0.f) * awp[p];
            wts[p * 4 + 3] = ((vx1 & vy1) ? (wx1 * wy1) : 0.f) * awp[p];
        }

        f32x4 acc = {0.f, 0.f, 0.f, 0.f};
#pragma unroll
        for (int i = 0; i < 16; ++i) {
            const f32x4 v = lds[idx[i]];
            acc.x += wts[i] * v.x;
            acc.y += wts[i] * v.y;
            acc.z += wts[i] * v.z;
            acc.w += wts[i] * v.w;
        }

        // out element offset /4: (b*NQ+q)*64 + h*8 + cg
        op[(size_t)(b * NQ + q) * 64 + h * 8 + cg] = acc;
    }
}

extern "C" void kernel_launch(void* const* d_in, const int* in_sizes, int n_in,
                              void* d_out, int out_size, void* d_ws, size_t ws_size,
                              hipStream_t stream) {
    const float* value = (const float*)d_in[0];
    // d_in[1] = value_spatial_shapes (int64), ignored: hardcoded 50x50
    const float* loc  = (const float*)d_in[2];
    const float* attw = (const float*)d_in[3];
    float* out = (float*)d_out;

    const int blocks = 8 * 16 * 8;   // cg * b * h = 1024
    deform_attn_kernel<<<blocks, TPB, 0, stream>>>(value, loc, attw, out);
}

// Round 3
// 115.620 us; speedup vs baseline: 1.3371x; 1.3371x over previous
//
#include <hip/hip_runtime.h>

// Single-level deformable attention.
// value: (bs=16, K=2500, H=8, D=32) f32
// sampling_locations: (bs, Q=2000, H=8, L=1, P=4, 2) f32
// attention_weights:  (bs, Q, H, 1, P) f32
// out: (bs, Q, H*D=256) f32
//
// R1: 32-lane/(b,q,h) scalar -> 49.7us, VALU-bound (75%).
// R2: 8-lane/(b,q,h) float4  -> 46us, VALU 24%, HBM 46%: latency-bound.
// R3: XCD swizzle: FETCH 138->27MB, dur 42us.
// R4: 2 q/thread + SGPR base: 42us, VGPR=32, compiler serialized (MLP~4).
// R5: inline-asm 32-deep MLP + counted vmcnt: 42.5us. Conclusion: 524MB
//     gather volume / 42us = 12.5 TB/s = L3 (Infinity Cache) BW ceiling.
//     Global-gather path is L3-throughput-capped; must stage in LDS.
// R6: LDS stage, 8-way channel split (16B/k slices): 74.5us. Staging at
//     16B/lane stride-1024 over-fetched 4x (FETCH 150MB), stores 16B
//     didn't merge (WRITE 51MB). LDS gather itself was fine.
// R7: fix staging geometry. Channel HALVES (64B/k): LDS 2500*64B=160,000B,
//     grid 256 = 16b x 8h x 2half, 1024 thr (16 waves/CU, 1 block/CU).
//     blockIdx%8==h => both half-siblings of (b,h) share an XCD: each
//     128B value line fetched once (sibling hits L2); 64B out stores
//     merge with sibling's to full lines. Thread=(query, ch-quad):
//     4 lanes share addr math, 16 ds_read_b128 + FMA per query.

#define FH 50
#define FW 50
#define KK (FH * FW)   // 2500
#define NH 8
#define ND 32
#define NQ 2000
#define NP 4
#define TPB 1024
#define QSLOTS (TPB / 4)               // 256 queries per pass
#define NPASS ((NQ + QSLOTS - 1) / QSLOTS)  // 8

typedef float f32x4 __attribute__((ext_vector_type(4)));

__global__ __launch_bounds__(TPB, 4) void deform_attn_kernel(
    const float* __restrict__ value,
    const float* __restrict__ loc,
    const float* __restrict__ attw,
    float* __restrict__ out)
{
    // blockIdx = half*128 + b*8 + h  (=> blockIdx % 8 == h for both halves)
    const int id = blockIdx.x;
    const int half = id >> 7;        // 0..1 (channel half: ch 0-15 or 16-31)
    const int bh = id & 127;
    const int b  = bh >> 3;
    const int h  = bh & 7;

    __shared__ f32x4 lds[KK * 4];    // 160,000 B: [k][quad] = 64B per k

    const int t = threadIdx.x;

    // ---- stage value[b, k, h, half*16 .. half*16+15] -> lds[k*4+quad] ----
    {
        // f32x4 units: per-k row stride = 64; this half starts at h*8+half*4
        const f32x4* __restrict__ src =
            (const f32x4*)value + (size_t)b * KK * 64 + h * 8 + half * 4;
#pragma unroll
        for (int i = 0; i < (KK * 4 + TPB - 1) / TPB; ++i) {   // 10 iters
            const int idx = i * TPB + t;                        // k*4 + q
            if (idx < KK * 4) {
                const int k = idx >> 2;
                const int q = idx & 3;
                lds[idx] = src[(size_t)k * 64 + q];
            }
        }
    }
    __syncthreads();

    const int quad = t & 3;          // which f32x4 of this 16-ch half
    const int qi = t >> 2;           // query slot 0..255

    const f32x4* __restrict__ lp = (const f32x4*)loc;
    const f32x4* __restrict__ ap = (const f32x4*)attw;
    f32x4* __restrict__ op = (f32x4*)out;

    for (int pass = 0; pass < NPASS; ++pass) {
        const int qq = pass * QSLOTS + qi;
        if (qq >= NQ) break;         // only pass 7 partially diverges

        const int gid = (b * NQ + qq) * NH + h;
        const f32x4 l0 = lp[(size_t)gid * 2 + 0];
        const f32x4 l1 = lp[(size_t)gid * 2 + 1];
        const f32x4 a4 = ap[gid];

        const float pxx[NP] = {l0.x, l0.z, l1.x, l1.z};
        const float pyy[NP] = {l0.y, l0.w, l1.y, l1.w};
        const float awp[NP] = {a4.x, a4.y, a4.z, a4.w};

        int   idx[16];
        float wts[16];
#pragma unroll
        for (int p = 0; p < NP; ++p) {
            const float fx = pxx[p] * (float)FW - 0.5f;
            const float fy = pyy[p] * (float)FH - 0.5f;
            const float x0f = floorf(fx);
            const float y0f = floorf(fy);
            const int x0 = (int)x0f, y0 = (int)y0f;
            const int x1 = x0 + 1, y1 = y0 + 1;
            const float wx1 = fx - x0f, wx0 = 1.f - wx1;
            const float wy1 = fy - y0f, wy0 = 1.f - wy1;

            const bool vx0 = (x0 >= 0) & (x0 < FW);
            const bool vx1 = (x1 >= 0) & (x1 < FW);
            const bool vy0 = (y0 >= 0) & (y0 < FH);
            const bool vy1 = (y1 >= 0) & (y1 < FH);

            const int cx0 = min(max(x0, 0), FW - 1);
            const int cx1 = min(max(x1, 0), FW - 1);
            const int cy0 = min(max(y0, 0), FH - 1);
            const int cy1 = min(max(y1, 0), FH - 1);

            idx[p * 4 + 0] = cy0 * FW + cx0;
            idx[p * 4 + 1] = cy0 * FW + cx1;
            idx[p * 4 + 2] = cy1 * FW + cx0;
            idx[p * 4 + 3] = cy1 * FW + cx1;

            wts[p * 4 + 0] = ((vx0 & vy0) ? (wx0 * wy0) : 0.f) * awp[p];
            wts[p * 4 + 1] = ((vx1 & vy0) ? (wx1 * wy0) : 0.f) * awp[p];
            wts[p * 4 + 2] = ((vx0 & vy1) ? (wx0 * wy1) : 0.f) * awp[p];
            wts[p * 4 + 3] = ((vx1 & vy1) ? (wx1 * wy1) : 0.f) * awp[p];
        }

        f32x4 acc = {0.f, 0.f, 0.f, 0.f};
#pragma unroll
        for (int i = 0; i < 16; ++i) {
            const f32x4 v = lds[idx[i] * 4 + quad];
            acc.x += wts[i] * v.x;
            acc.y += wts[i] * v.y;
            acc.z += wts[i] * v.z;
            acc.w += wts[i] * v.w;
        }

        // out f32x4 index: (b*NQ+q)*64 + h*8 + half*4 + quad
        op[(size_t)(b * NQ + qq) * 64 + h * 8 + half * 4 + quad] = acc;
    }
}

extern "C" void kernel_launch(void* const* d_in, const int* in_sizes, int n_in,
                              void* d_out, int out_size, void* d_ws, size_t ws_size,
                              hipStream_t stream) {
    const float* value = (const float*)d_in[0];
    // d_in[1] = value_spatial_shapes (int64), ignored: hardcoded 50x50
    const float* loc  = (const float*)d_in[2];
    const float* attw = (const float*)d_in[3];
    float* out = (float*)d_out;

    const int blocks = 2 * 16 * 8;   // half * b * h = 256
    deform_attn_kernel<<<blocks, TPB, 0, stream>>>(value, loc, attw, out);
}